// Round 1
// baseline (6081.296 us; speedup 1.0000x reference)
//
#include <hip/hip_runtime.h>
#include <hip/hip_bf16.h>

typedef __attribute__((ext_vector_type(8))) short s16x8;
typedef __attribute__((ext_vector_type(4))) float f32x4;

// ---------------------------------------------------------------------------
// fp32 -> bf16 conversion (vectorized, grid-stride)
// ---------------------------------------------------------------------------
__global__ void cvt_f32_to_bf16_kernel(const float* __restrict__ in,
                                       __hip_bfloat16* __restrict__ out,
                                       long n) {
  long i = (long)blockIdx.x * blockDim.x + threadIdx.x;
  long stride = (long)gridDim.x * blockDim.x;
  const float4* p4 = (const float4*)in;
  for (long j = i; j * 8 < n; j += stride) {
    float4 a = p4[j * 2];
    float4 b = p4[j * 2 + 1];
    union { s16x8 v; __hip_bfloat162 h2[4]; } w;
    w.h2[0] = __float22bfloat162_rn(make_float2(a.x, a.y));
    w.h2[1] = __float22bfloat162_rn(make_float2(a.z, a.w));
    w.h2[2] = __float22bfloat162_rn(make_float2(b.x, b.y));
    w.h2[3] = __float22bfloat162_rn(make_float2(b.z, b.w));
    *(s16x8*)(out + j * 8) = w.v;
  }
}

// ---------------------------------------------------------------------------
// Fused gate+up GEMM: h = silu(x @ Wg^T) * (x @ Wu^T), W dequantized on the fly
// A: [Mc][4096] bf16 (ws). B: qw [11008][4096] int32 (values 0..15).
// Tile: BM=128, BN=128, BK=64. 4 waves, each computes 64x64 per matrix.
// ---------------------------------------------------------------------------
__global__ __launch_bounds__(256, 2)
void gateup_kernel(const __hip_bfloat16* __restrict__ Xb,
                   const int* __restrict__ Qg, const int* __restrict__ Qu,
                   const float* __restrict__ Sg, const float* __restrict__ Zg,
                   const float* __restrict__ Su, const float* __restrict__ Zu,
                   __hip_bfloat16* __restrict__ Hout,
                   int mblocks) {
  constexpr int H = 4096, I = 11008, G = 32;  // G = H/128 groups per row
  const int bid = blockIdx.x;
  const int nb = bid / mblocks;
  const int mb = bid - nb * mblocks;
  const int m0 = mb * 128, n0 = nb * 128;
  const int tid = threadIdx.x;
  const int lane = tid & 63;
  const int wave = tid >> 6;
  const int wm = (wave >> 1) * 64, wn = (wave & 1) * 64;
  const int l15 = lane & 15, lq = lane >> 4;

  __shared__ __hip_bfloat16 As[128][64];
  __shared__ __hip_bfloat16 Bgs[128][64];
  __shared__ __hip_bfloat16 Bus[128][64];

  f32x4 accg[4][4], accu[4][4];
#pragma unroll
  for (int i = 0; i < 4; ++i)
#pragma unroll
    for (int j = 0; j < 4; ++j) {
      accg[i][j] = {0.f, 0.f, 0.f, 0.f};
      accu[i][j] = {0.f, 0.f, 0.f, 0.f};
    }

  const int arow = tid >> 3, acol = (tid & 7) * 8;  // staging coords

  for (int k0 = 0; k0 < H; k0 += 64) {
    __syncthreads();
    // ---- stage A (global_load_lds, 16B per lane, 4 calls) ----
#pragma unroll
    for (int c = 0; c < 4; ++c) {
      const __hip_bfloat16* src = Xb + (size_t)(m0 + c * 32 + arow) * H + (k0 + acol);
      __hip_bfloat16* dst = &As[0][0] + (size_t)(c * 256 + tid) * 8;
      __builtin_amdgcn_global_load_lds((const __attribute__((address_space(1))) void*)src,
                                       (__attribute__((address_space(3))) void*)dst,
                                       16, 0, 0);
    }
    // ---- stage B gate & up: load int32, dequant -> bf16, ds_write ----
    const int gidx = k0 >> 7;  // one group per K-tile (64 | 128)
#pragma unroll
    for (int it = 0; it < 4; ++it) {
      const int r = it * 32 + arow;
      const int rg = n0 + r;
      {
        const int* qp = Qg + (size_t)rg * H + (k0 + acol);
        int4 q0 = *(const int4*)qp;
        int4 q1 = *(const int4*)(qp + 4);
        const float s = Sg[rg * G + gidx];
        const float zs = Zg[rg * G + gidx] * s;
        union { s16x8 v; __hip_bfloat162 h2[4]; } w;
        w.h2[0] = __float22bfloat162_rn(make_float2((float)q0.x * s - zs, (float)q0.y * s - zs));
        w.h2[1] = __float22bfloat162_rn(make_float2((float)q0.z * s - zs, (float)q0.w * s - zs));
        w.h2[2] = __float22bfloat162_rn(make_float2((float)q1.x * s - zs, (float)q1.y * s - zs));
        w.h2[3] = __float22bfloat162_rn(make_float2((float)q1.z * s - zs, (float)q1.w * s - zs));
        *(s16x8*)&Bgs[r][acol] = w.v;
      }
      {
        const int* qp = Qu + (size_t)rg * H + (k0 + acol);
        int4 q0 = *(const int4*)qp;
        int4 q1 = *(const int4*)(qp + 4);
        const float s = Su[rg * G + gidx];
        const float zs = Zu[rg * G + gidx] * s;
        union { s16x8 v; __hip_bfloat162 h2[4]; } w;
        w.h2[0] = __float22bfloat162_rn(make_float2((float)q0.x * s - zs, (float)q0.y * s - zs));
        w.h2[1] = __float22bfloat162_rn(make_float2((float)q0.z * s - zs, (float)q0.w * s - zs));
        w.h2[2] = __float22bfloat162_rn(make_float2((float)q1.x * s - zs, (float)q1.y * s - zs));
        w.h2[3] = __float22bfloat162_rn(make_float2((float)q1.z * s - zs, (float)q1.w * s - zs));
        *(s16x8*)&Bus[r][acol] = w.v;
      }
    }
    __syncthreads();
    // ---- MFMA over BK=64 (two K=32 steps) ----
#pragma unroll
    for (int kk = 0; kk < 2; ++kk) {
      s16x8 af[4], bgf[4], buf_[4];
#pragma unroll
      for (int i = 0; i < 4; ++i)
        af[i] = *(const s16x8*)&As[wm + i * 16 + l15][kk * 32 + lq * 8];
#pragma unroll
      for (int j = 0; j < 4; ++j) {
        bgf[j]  = *(const s16x8*)&Bgs[wn + j * 16 + l15][kk * 32 + lq * 8];
        buf_[j] = *(const s16x8*)&Bus[wn + j * 16 + l15][kk * 32 + lq * 8];
      }
#pragma unroll
      for (int i = 0; i < 4; ++i)
#pragma unroll
        for (int j = 0; j < 4; ++j) {
          accg[i][j] = __builtin_amdgcn_mfma_f32_16x16x32_bf16(af[i], bgf[j], accg[i][j], 0, 0, 0);
          accu[i][j] = __builtin_amdgcn_mfma_f32_16x16x32_bf16(af[i], buf_[j], accu[i][j], 0, 0, 0);
        }
    }
  }
  // ---- epilogue: h = silu(g)*u -> bf16 ----
#pragma unroll
  for (int i = 0; i < 4; ++i)
#pragma unroll
    for (int j = 0; j < 4; ++j)
#pragma unroll
      for (int r = 0; r < 4; ++r) {
        const int row = m0 + wm + i * 16 + lq * 4 + r;
        const int col = n0 + wn + j * 16 + l15;
        float g = accg[i][j][r];
        float u = accu[i][j][r];
        float hv = (g / (1.f + __expf(-g))) * u;
        Hout[(size_t)row * I + col] = __float2bfloat16(hv);
      }
}

// ---------------------------------------------------------------------------
// Down GEMM: out = h @ Wd^T. A: [Mc][11008] bf16 (ws). Qd: [4096][11008] int32.
// ---------------------------------------------------------------------------
__global__ __launch_bounds__(256, 2)
void down_kernel(const __hip_bfloat16* __restrict__ Hin,
                 const int* __restrict__ Qd,
                 const float* __restrict__ Sd, const float* __restrict__ Zd,
                 float* __restrict__ Out,
                 int mblocks) {
  constexpr int K = 11008, N = 4096, G = 86;  // G = K/128
  const int bid = blockIdx.x;
  const int nb = bid / mblocks;
  const int mb = bid - nb * mblocks;
  const int m0 = mb * 128, n0 = nb * 128;
  const int tid = threadIdx.x;
  const int lane = tid & 63;
  const int wave = tid >> 6;
  const int wm = (wave >> 1) * 64, wn = (wave & 1) * 64;
  const int l15 = lane & 15, lq = lane >> 4;

  __shared__ __hip_bfloat16 As[128][64];
  __shared__ __hip_bfloat16 Bs[128][64];

  f32x4 acc[4][4];
#pragma unroll
  for (int i = 0; i < 4; ++i)
#pragma unroll
    for (int j = 0; j < 4; ++j) acc[i][j] = {0.f, 0.f, 0.f, 0.f};

  const int arow = tid >> 3, acol = (tid & 7) * 8;

  for (int k0 = 0; k0 < K; k0 += 64) {
    __syncthreads();
#pragma unroll
    for (int c = 0; c < 4; ++c) {
      const __hip_bfloat16* src = Hin + (size_t)(m0 + c * 32 + arow) * K + (k0 + acol);
      __hip_bfloat16* dst = &As[0][0] + (size_t)(c * 256 + tid) * 8;
      __builtin_amdgcn_global_load_lds((const __attribute__((address_space(1))) void*)src,
                                       (__attribute__((address_space(3))) void*)dst,
                                       16, 0, 0);
    }
    const int gidx = k0 >> 7;
#pragma unroll
    for (int it = 0; it < 4; ++it) {
      const int r = it * 32 + arow;
      const int rg = n0 + r;
      const int* qp = Qd + (size_t)rg * K + (k0 + acol);
      int4 q0 = *(const int4*)qp;
      int4 q1 = *(const int4*)(qp + 4);
      const float s = Sd[rg * G + gidx];
      const float zs = Zd[rg * G + gidx] * s;
      union { s16x8 v; __hip_bfloat162 h2[4]; } w;
      w.h2[0] = __float22bfloat162_rn(make_float2((float)q0.x * s - zs, (float)q0.y * s - zs));
      w.h2[1] = __float22bfloat162_rn(make_float2((float)q0.z * s - zs, (float)q0.w * s - zs));
      w.h2[2] = __float22bfloat162_rn(make_float2((float)q1.x * s - zs, (float)q1.y * s - zs));
      w.h2[3] = __float22bfloat162_rn(make_float2((float)q1.z * s - zs, (float)q1.w * s - zs));
      *(s16x8*)&Bs[r][acol] = w.v;
    }
    __syncthreads();
#pragma unroll
    for (int kk = 0; kk < 2; ++kk) {
      s16x8 af[4], bf[4];
#pragma unroll
      for (int i = 0; i < 4; ++i)
        af[i] = *(const s16x8*)&As[wm + i * 16 + l15][kk * 32 + lq * 8];
#pragma unroll
      for (int j = 0; j < 4; ++j)
        bf[j] = *(const s16x8*)&Bs[wn + j * 16 + l15][kk * 32 + lq * 8];
#pragma unroll
      for (int i = 0; i < 4; ++i)
#pragma unroll
        for (int j = 0; j < 4; ++j)
          acc[i][j] = __builtin_amdgcn_mfma_f32_16x16x32_bf16(af[i], bf[j], acc[i][j], 0, 0, 0);
    }
  }
#pragma unroll
  for (int i = 0; i < 4; ++i)
#pragma unroll
    for (int j = 0; j < 4; ++j)
#pragma unroll
      for (int r = 0; r < 4; ++r) {
        const int row = m0 + wm + i * 16 + lq * 4 + r;
        const int col = n0 + wn + j * 16 + l15;
        Out[(size_t)row * N + col] = acc[i][j][r];
      }
}

// ---------------------------------------------------------------------------
extern "C" void kernel_launch(void* const* d_in, const int* in_sizes, int n_in,
                              void* d_out, int out_size, void* d_ws, size_t ws_size,
                              hipStream_t stream) {
  const float* x  = (const float*)d_in[0];
  const int* qg   = (const int*)d_in[1];
  const int* qu   = (const int*)d_in[2];
  const int* qd   = (const int*)d_in[3];
  const float* sg = (const float*)d_in[4];
  const float* zg = (const float*)d_in[5];
  const float* su = (const float*)d_in[6];
  const float* zu = (const float*)d_in[7];
  const float* sd = (const float*)d_in[8];
  const float* zd = (const float*)d_in[9];
  float* out = (float*)d_out;

  const int M = 4 * 2048, H = 4096, I = 11008;

  // Chunk M so x_bf16 chunk + h chunk fit in workspace.
  const size_t per_row = (size_t)(H + I) * 2;
  long mc = (long)(ws_size / per_row);
  mc &= ~127L;
  if (mc > M) mc = M;
  if (mc < 128) mc = 128;  // minimum granularity; ws_size is expected to cover this
  const int Mc = (int)mc;

  __hip_bfloat16* wsx = (__hip_bfloat16*)d_ws;
  __hip_bfloat16* wsh = (__hip_bfloat16*)((char*)d_ws + (size_t)Mc * H * 2);

  for (int mbase = 0; mbase < M; mbase += Mc) {
    const int rows = (M - mbase < Mc) ? (M - mbase) : Mc;
    const int mblocks = rows / 128;
    const long n = (long)rows * H;
    cvt_f32_to_bf16_kernel<<<1024, 256, 0, stream>>>(x + (size_t)mbase * H, wsx, n);
    gateup_kernel<<<(I / 128) * mblocks, 256, 0, stream>>>(
        wsx, qg, qu, sg, zg, su, zu, wsh, mblocks);
    down_kernel<<<(H / 128) * mblocks, 256, 0, stream>>>(
        wsh, qd, sd, zd, out + (size_t)mbase * H, mblocks);
  }
}